// Round 3
// baseline (322.869 us; speedup 1.0000x reference)
//
#include <hip/hip_runtime.h>
#include <math.h>

#define N_NODES 100000
#define N_EDGES 1600000
#define F_INDIM 256
#define HID 64
#define NCLS 40
#define NBKT 196         // ceil(N_NODES/512) coarse buckets of 512 dst nodes
#define NBLKA 196        // binning blocks (EPB edges each)
#define EPB 8192         // edges per binning block
#define CAPB 96          // per-(bucket,block) slot capacity (binomial mean 42, +8 sigma)
#define REGSZ 12544      // esrc slots per bucket: 8192 + slack + 512*7 pad, mult of 8
#define ECAP 10240       // LDS edge-cache capacity per bucket (40 KB)
#define NGEMM1 391       // ceil((N_NODES+1)/256) row-tiles of 256
#define KP 264           // padded k-stride for wt (2-way bank aliasing only = free)
#define AP 72            // padded k-stride for gemm2 tiles

typedef __attribute__((ext_vector_type(8))) short short8;
typedef __attribute__((ext_vector_type(4))) float floatx4;

// ---- bf16 helpers (RNE) ----
__device__ __forceinline__ unsigned short f2bf(float f) {
  unsigned u = __float_as_uint(f);
  unsigned r = (u + 0x7FFFu + ((u >> 16) & 1u)) >> 16;
  return (unsigned short)r;
}
// accumulate 8 packed bf16 (one 16B quad of a row) into 8 fp32 accumulators
__device__ __forceinline__ void add8(float* a, uint4 u) {
  a[0] += __uint_as_float(u.x << 16);
  a[1] += __uint_as_float(u.x & 0xFFFF0000u);
  a[2] += __uint_as_float(u.y << 16);
  a[3] += __uint_as_float(u.y & 0xFFFF0000u);
  a[4] += __uint_as_float(u.z << 16);
  a[5] += __uint_as_float(u.z & 0xFFFF0000u);
  a[6] += __uint_as_float(u.w << 16);
  a[7] += __uint_as_float(u.w & 0xFFFF0000u);
}

// ---------------- kernel 1: binA (deterministic, single pass) ∥ gemm1 ----------------
// blocks [0,NBLKA): bin EPB edges into per-(bucket,block) regions — no global atomics,
//                   no histogram pass (edge list read ONCE).
// blocks [NBLKA, NBLKA+NGEMM1): h1b = bf16(x @ W1) UNSCALED (dis applied by k_build2),
//                   256 rows per 1024-thread block; row N_NODES written as zeros.

__global__ __launch_bounds__(1024) void k_pre(const int* __restrict__ row,
                                              const int* __restrict__ col,
                                              const float* __restrict__ x,
                                              const float* __restrict__ W1,
                                              unsigned int* __restrict__ bktdata,
                                              int* __restrict__ cnt,
                                              unsigned short* __restrict__ h1b) {
  __shared__ union {
    int cur[NBKT];
    unsigned short wt[HID * KP];   // wt[n][k] = bf16(W1[k][n])
  } sm;
  const int t = threadIdx.x;

  if (blockIdx.x < NBLKA) {
    // ---- binning path ----
    const int blk = blockIdx.x;
    const int e0 = blk * EPB;
    const int n = min(EPB, N_EDGES - e0);
    if (t < NBKT) sm.cur[t] = 0;
    __syncthreads();
    for (int i = t * 4; i < n; i += 4096) {
      int4 c4 = *(const int4*)&col[e0 + i];
      int4 r4 = *(const int4*)&row[e0 + i];
#pragma unroll
      for (int k = 0; k < 4; ++k) {
        int c = (k == 0) ? c4.x : (k == 1) ? c4.y : (k == 2) ? c4.z : c4.w;
        int r = (k == 0) ? r4.x : (k == 1) ? r4.y : (k == 2) ? r4.z : r4.w;
        int b = c >> 9;
        int p = atomicAdd(&sm.cur[b], 1);
        if (p < CAPB)
          bktdata[((size_t)b * NBLKA + blk) * CAPB + p] =
              ((unsigned)(c & 511) << 17) | (unsigned)r;
      }
    }
    __syncthreads();
    if (t < NBKT) cnt[t * NBLKA + blk] = min(sm.cur[t], CAPB);
  } else {
    // ---- gemm1 path (unscaled) ----
    const int lane = t & 63;
    const int w = t >> 6;          // 0..15
    const int quad = lane >> 4;
    const int l15 = lane & 15;
    const int rowBase = (blockIdx.x - NBLKA) * 256;
#pragma unroll
    for (int i = 0; i < 4; ++i) {
      int f = t + 1024 * i;        // 0..4095 quads of W1
      int k = f >> 4;
      int n0 = (f & 15) * 4;
      float4 v = *(const float4*)&W1[(size_t)k * HID + n0];
      sm.wt[(n0 + 0) * KP + k] = f2bf(v.x);
      sm.wt[(n0 + 1) * KP + k] = f2bf(v.y);
      sm.wt[(n0 + 2) * KP + k] = f2bf(v.z);
      sm.wt[(n0 + 3) * KP + k] = f2bf(v.w);
    }
    __syncthreads();

    const int ar = rowBase + w * 16 + l15;
    const float* xrow =
        x + (size_t)((ar < N_NODES) ? ar : N_NODES - 1) * F_INDIM + quad * 8;

    floatx4 acc[4];
#pragma unroll
    for (int c = 0; c < 4; ++c) acc[c] = (floatx4){0.f, 0.f, 0.f, 0.f};

#pragma unroll
    for (int kc = 0; kc < F_INDIM; kc += 32) {
      const float4 va = *(const float4*)(xrow + kc);
      const float4 vb = *(const float4*)(xrow + kc + 4);
      short8 a;
      a[0] = (short)f2bf(va.x); a[1] = (short)f2bf(va.y);
      a[2] = (short)f2bf(va.z); a[3] = (short)f2bf(va.w);
      a[4] = (short)f2bf(vb.x); a[5] = (short)f2bf(vb.y);
      a[6] = (short)f2bf(vb.z); a[7] = (short)f2bf(vb.w);
#pragma unroll
      for (int c = 0; c < 4; ++c) {
        const short8 bfr = *(const short8*)&sm.wt[(c * 16 + l15) * KP + kc + quad * 8];
        acc[c] = __builtin_amdgcn_mfma_f32_16x16x32_bf16(a, bfr, acc[c], 0, 0, 0);
      }
    }

#pragma unroll
    for (int reg = 0; reg < 4; ++reg) {
      int gr = rowBase + w * 16 + quad * 4 + reg;
      if (gr <= N_NODES) {
        bool real = gr < N_NODES;
#pragma unroll
        for (int c = 0; c < 4; ++c)
          h1b[(size_t)gr * HID + c * 16 + l15] =
              real ? f2bf(acc[c][reg]) : (unsigned short)0;
      }
    }
  }
}

// ---------------- kernel 2: build CSR + scale h1b (per bucket of 512 dst nodes) -----
// Gathers the bucket's 196 sub-segments into an LDS edge cache (196-entry scan +
// binary search), then hist + dis + padded-8 scan + placement. Tail phase scales the
// bucket's own h1b rows in place by dis[n] so agg kernels need NO per-edge dis loads.

__global__ __launch_bounds__(1024) void k_build2(const int* __restrict__ cnt,
                                                 const unsigned int* __restrict__ bktdata,
                                                 float* __restrict__ dis,
                                                 int* __restrict__ start,
                                                 int* __restrict__ endi,
                                                 int* __restrict__ esrc,
                                                 unsigned short* __restrict__ h1b) {
  __shared__ int scnt[NBLKA];
  __shared__ int sscan[NBLKA];              // inclusive scan of scnt
  __shared__ unsigned int ecache[ECAP];     // bucket's edges, concatenated
  __shared__ int h[512];
  __shared__ int curs[512];
  __shared__ int sbase[512];
  __shared__ float sdis[512];
  const int b = blockIdx.x, t = threadIdx.x;

  if (t < 512) { h[t] = 0; curs[t] = 0; }
  if (t < NBLKA) { int c = cnt[b * NBLKA + t]; scnt[t] = c; sscan[t] = c; }
  __syncthreads();
  // inclusive Hillis-Steele over 196 entries (8 steps)
#pragma unroll
  for (int off = 1; off < NBLKA; off <<= 1) {
    int u = (t < NBLKA && t >= off) ? sscan[t - off] : 0;
    __syncthreads();
    if (t < NBLKA) sscan[t] += u;
    __syncthreads();
  }
  const int total = min(sscan[NBLKA - 1], ECAP);

  // flat copy sub-segments -> ecache via binary search over sscan
  for (int j = t; j < total; j += 1024) {
    int lo = 0, hi = NBLKA - 1;
    while (lo < hi) {                        // <= 8 iters
      int mid = (lo + hi) >> 1;
      if (sscan[mid] <= j) lo = mid + 1; else hi = mid;
    }
    int segoff = j - (sscan[lo] - scnt[lo]);
    ecache[j] = bktdata[((size_t)b * NBLKA + lo) * CAPB + segoff];
  }
  __syncthreads();

  for (int i = t; i < total; i += 1024) atomicAdd(&h[ecache[i] >> 17], 1);
  __syncthreads();

  int c0 = 0, p0 = 0;
  if (t < 512) {
    const int n0 = b * 512 + t;
    c0 = h[t];
    p0 = (c0 + 7) & ~7;                      // pad segment to multiple of 8
    float dv = rsqrtf((float)(c0 + 1));
    sdis[t] = (n0 < N_NODES) ? dv : 0.f;
    if (n0 < N_NODES) dis[n0] = dv;
    h[t] = p0;                               // scan PADDED counts
  }
  __syncthreads();
  // inclusive Hillis-Steele over 512 entries (9 steps)
#pragma unroll
  for (int off = 1; off < 512; off <<= 1) {
    int u = (t < 512 && t >= off) ? h[t - off] : 0;
    __syncthreads();
    if (t < 512) h[t] += u;
    __syncthreads();
  }
  if (t < 512) {
    const int n0 = b * 512 + t;
    const int sb0 = b * REGSZ + h[t] - p0;   // exclusive padded start (8-aligned)
    sbase[t] = sb0;
    if (n0 < N_NODES) { start[n0] = sb0; endi[n0] = sb0 + c0; }
    for (int k = c0; k < p0; ++k) esrc[sb0 + k] = N_NODES;  // dummy fill
  }
  __syncthreads();

  for (int i = t; i < total; i += 1024) {
    unsigned u = ecache[i];
    int ld = u >> 17;
    int src = u & 0x1FFFF;
    int pos = sbase[ld] + atomicAdd(&curs[ld], 1);
    esrc[pos] = src;
  }

  // ---- tail: scale this bucket's h1b rows in place: h1b[n] *= dis[n] ----
  // (sdis was committed before an earlier __syncthreads; no extra barrier needed)
  uint4* h4 = (uint4*)h1b;
  for (int i = t; i < 512 * 8; i += 1024) {
    int r = i >> 3, qq = i & 7;
    int n0 = b * 512 + r;
    if (n0 < N_NODES) {
      float d = sdis[r];
      uint4 u = h4[(size_t)n0 * 8 + qq];
      float f0 = __uint_as_float(u.x << 16) * d;
      float f1 = __uint_as_float(u.x & 0xFFFF0000u) * d;
      float f2 = __uint_as_float(u.y << 16) * d;
      float f3 = __uint_as_float(u.y & 0xFFFF0000u) * d;
      float f4 = __uint_as_float(u.z << 16) * d;
      float f5 = __uint_as_float(u.z & 0xFFFF0000u) * d;
      float f6 = __uint_as_float(u.w << 16) * d;
      float f7 = __uint_as_float(u.w & 0xFFFF0000u) * d;
      u.x = (unsigned)f2bf(f0) | ((unsigned)f2bf(f1) << 16);
      u.y = (unsigned)f2bf(f2) | ((unsigned)f2bf(f3) << 16);
      u.z = (unsigned)f2bf(f4) | ((unsigned)f2bf(f5) << 16);
      u.w = (unsigned)f2bf(f6) | ((unsigned)f2bf(f7) << 16);
      h4[(size_t)n0 * 8 + qq] = u;
    }
  }
}

// ---------------- agg1: ab = bf16(relu(dis[n]*(self+sum) + b1)) ----------------
// one node per 8-lane group; barrier-free; h1b rows are pre-scaled by dis[src].

__global__ __launch_bounds__(256) void k_agg1(const int* __restrict__ esrc,
                                              const int* __restrict__ start,
                                              const int* __restrict__ endi,
                                              const float* __restrict__ dis,
                                              const unsigned short* __restrict__ h1b,
                                              const float* __restrict__ b1,
                                              unsigned short* __restrict__ ab) {
  int gid = blockIdx.x * 256 + threadIdx.x;
  int node = gid >> 3;
  int q = gid & 7;
  if (node >= N_NODES) return;
  const uint4* hp4 = (const uint4*)h1b;    // row = 8 quads of 16B
  const int s = start[node];
  const int e8 = (endi[node] + 7) & ~7;
  float acc[8];
#pragma unroll
  for (int j = 0; j < 8; ++j) acc[j] = 0.f;
  for (int i = s; i < e8; i += 8) {        // segments padded to 8: no remainder
    int4 sa = *(const int4*)&esrc[i];
    int4 sb = *(const int4*)&esrc[i + 4];
    uint4 u0 = hp4[(size_t)sa.x * 8 + q];
    uint4 u1 = hp4[(size_t)sa.y * 8 + q];
    uint4 u2 = hp4[(size_t)sa.z * 8 + q];
    uint4 u3 = hp4[(size_t)sa.w * 8 + q];
    uint4 u4 = hp4[(size_t)sb.x * 8 + q];
    uint4 u5 = hp4[(size_t)sb.y * 8 + q];
    uint4 u6 = hp4[(size_t)sb.z * 8 + q];
    uint4 u7 = hp4[(size_t)sb.w * 8 + q];
    add8(acc, u0); add8(acc, u1); add8(acc, u2); add8(acc, u3);
    add8(acc, u4); add8(acc, u5); add8(acc, u6); add8(acc, u7);
  }
  uint4 us = hp4[(size_t)node * 8 + q];
  add8(acc, us);                           // self term (pre-scaled)
  float d = dis[node];
  float4 ba = *(const float4*)&b1[q * 8];
  float4 bb = *(const float4*)&b1[q * 8 + 4];
  float v0 = fmaxf(d * acc[0] + ba.x, 0.f);
  float v1 = fmaxf(d * acc[1] + ba.y, 0.f);
  float v2 = fmaxf(d * acc[2] + ba.z, 0.f);
  float v3 = fmaxf(d * acc[3] + ba.w, 0.f);
  float v4 = fmaxf(d * acc[4] + bb.x, 0.f);
  float v5 = fmaxf(d * acc[5] + bb.y, 0.f);
  float v6 = fmaxf(d * acc[6] + bb.z, 0.f);
  float v7 = fmaxf(d * acc[7] + bb.w, 0.f);
  uint4 o;
  o.x = (unsigned)f2bf(v0) | ((unsigned)f2bf(v1) << 16);
  o.y = (unsigned)f2bf(v2) | ((unsigned)f2bf(v3) << 16);
  o.z = (unsigned)f2bf(v4) | ((unsigned)f2bf(v5) << 16);
  o.w = (unsigned)f2bf(v6) | ((unsigned)f2bf(v7) << 16);
  ((uint4*)ab)[(size_t)node * 8 + q] = o;
}

// ---------------- GEMM2 (MFMA): gb = bf16(dis[row] * (ab @ W2)), rows padded 64 ----
// cols 40..47 are genuine zeros via padded W2; cols 48..63 never read by agg2 (q<5).

__global__ __launch_bounds__(256) void k_gemm2(const unsigned short* __restrict__ ab,
                                               const float* __restrict__ W2,
                                               const float* __restrict__ dis,
                                               unsigned short* __restrict__ gb) {
  __shared__ unsigned short as[64 * AP];
  __shared__ unsigned short w2t[48 * AP];   // w2t[n][k] = bf16(W2[k][n]), 0-pad n>=40
  const int tid = threadIdx.x;
  const int lane = tid & 63;
  const int w = tid >> 6;
  const int quad = lane >> 4;
  const int l15 = lane & 15;
  const int rowBase = blockIdx.x * 64;

  for (int i = tid; i < 48 * 64; i += 256) {
    int n = i >> 6;
    int k = i & 63;
    w2t[n * AP + k] = (n < NCLS) ? f2bf(W2[(size_t)k * NCLS + n]) : (unsigned short)0;
  }
#pragma unroll
  for (int i = 0; i < 2; ++i) {
    int f = tid + 256 * i;
    int r = f >> 3;
    int q = f & 7;
    int gr = rowBase + r;
    short8 v = (short8){0, 0, 0, 0, 0, 0, 0, 0};
    if (gr < N_NODES) v = *(const short8*)&ab[(size_t)gr * HID + q * 8];
    *(short8*)&as[r * AP + q * 8] = v;
  }
  __syncthreads();

  floatx4 acc[3];
#pragma unroll
  for (int c = 0; c < 3; ++c) acc[c] = (floatx4){0.f, 0.f, 0.f, 0.f};

#pragma unroll
  for (int kh = 0; kh < 2; ++kh) {
    const short8 a = *(const short8*)&as[(w * 16 + l15) * AP + kh * 32 + quad * 8];
#pragma unroll
    for (int c = 0; c < 3; ++c) {
      const short8 bfr = *(const short8*)&w2t[(c * 16 + l15) * AP + kh * 32 + quad * 8];
      acc[c] = __builtin_amdgcn_mfma_f32_16x16x32_bf16(a, bfr, acc[c], 0, 0, 0);
    }
  }

#pragma unroll
  for (int reg = 0; reg < 4; ++reg) {
    int gr = rowBase + w * 16 + quad * 4 + reg;
    if (gr < N_NODES) {
      float d = dis[gr];
#pragma unroll
      for (int c = 0; c < 3; ++c)
        gb[(size_t)gr * 64 + c * 16 + l15] = f2bf(d * acc[c][reg]);
    }
  }
}

// ---------------- agg2 + log_softmax fused: one node per 8-lane group ----------
// only lanes q<5 gather (bytes 0..79 = 40 real classes): 37.5% less gather traffic.

__global__ __launch_bounds__(256) void k_agg2ls(const int* __restrict__ esrc,
                                                const int* __restrict__ start,
                                                const int* __restrict__ endi,
                                                const float* __restrict__ dis,
                                                const unsigned short* __restrict__ gb,
                                                const float* __restrict__ b2,
                                                float* __restrict__ out) {
  int gid = blockIdx.x * 256 + threadIdx.x;
  int node = gid >> 3;
  int q = gid & 7;
  if (node >= N_NODES) return;
  const bool wr = q < 5;
  float acc[8];
#pragma unroll
  for (int j = 0; j < 8; ++j) acc[j] = 0.f;
  if (wr) {
    const uint4* gp4 = (const uint4*)gb;
    const int s = start[node];
    const int e8 = (endi[node] + 7) & ~7;
    for (int i = s; i < e8; i += 8) {        // padded to 8: no remainder branch
      int4 sa = *(const int4*)&esrc[i];
      int4 sb = *(const int4*)&esrc[i + 4];
      uint4 u0 = gp4[(size_t)sa.x * 8 + q];
      uint4 u1 = gp4[(size_t)sa.y * 8 + q];
      uint4 u2 = gp4[(size_t)sa.z * 8 + q];
      uint4 u3 = gp4[(size_t)sa.w * 8 + q];
      uint4 u4 = gp4[(size_t)sb.x * 8 + q];
      uint4 u5 = gp4[(size_t)sb.y * 8 + q];
      uint4 u6 = gp4[(size_t)sb.z * 8 + q];
      uint4 u7 = gp4[(size_t)sb.w * 8 + q];
      add8(acc, u0); add8(acc, u1); add8(acc, u2); add8(acc, u3);
      add8(acc, u4); add8(acc, u5); add8(acc, u6); add8(acc, u7);
    }
    uint4 us = gp4[(size_t)node * 8 + q];
    add8(acc, us);                           // self (pre-scaled in gb)
  }
  float v0 = 0.f, v1 = 0.f, v2 = 0.f, v3 = 0.f, v4 = 0.f, v5 = 0.f, v6 = 0.f, v7 = 0.f;
  float m = -INFINITY;
  if (wr) {
    float d = dis[node];
    float4 ba = *(const float4*)&b2[q * 8];
    float4 bb = *(const float4*)&b2[q * 8 + 4];
    v0 = d * acc[0] + ba.x;
    v1 = d * acc[1] + ba.y;
    v2 = d * acc[2] + ba.z;
    v3 = d * acc[3] + ba.w;
    v4 = d * acc[4] + bb.x;
    v5 = d * acc[5] + bb.y;
    v6 = d * acc[6] + bb.z;
    v7 = d * acc[7] + bb.w;
    m = fmaxf(fmaxf(fmaxf(v0, v1), fmaxf(v2, v3)),
              fmaxf(fmaxf(v4, v5), fmaxf(v6, v7)));
  }
#pragma unroll
  for (int off = 1; off < 8; off <<= 1) m = fmaxf(m, __shfl_xor(m, off));
  float el = 0.f;
  if (wr) {
    el = __expf(v0 - m) + __expf(v1 - m) + __expf(v2 - m) + __expf(v3 - m) +
         __expf(v4 - m) + __expf(v5 - m) + __expf(v6 - m) + __expf(v7 - m);
  }
#pragma unroll
  for (int off = 1; off < 8; off <<= 1) el += __shfl_xor(el, off);
  float ls = logf(el);
  if (wr) {
    float4 o1 = make_float4(v0 - m - ls, v1 - m - ls, v2 - m - ls, v3 - m - ls);
    float4 o2 = make_float4(v4 - m - ls, v5 - m - ls, v6 - m - ls, v7 - m - ls);
    *(float4*)&out[(size_t)node * NCLS + q * 8] = o1;
    *(float4*)&out[(size_t)node * NCLS + q * 8 + 4] = o2;
  }
}

// ---------------- launch ----------------

extern "C" void kernel_launch(void* const* d_in, const int* in_sizes, int n_in,
                              void* d_out, int out_size, void* d_ws, size_t ws_size,
                              hipStream_t stream) {
  const float* x  = (const float*)d_in[0];
  const int*   ei = (const int*)d_in[1];
  const float* W1 = (const float*)d_in[2];
  const float* b1 = (const float*)d_in[3];
  const float* W2 = (const float*)d_in[4];
  const float* b2 = (const float*)d_in[5];
  float* out = (float*)d_out;

  const int* row = ei;             // edge_index[0] = src
  const int* col = ei + N_EDGES;   // edge_index[1] = dst

  // workspace layout (~51 MB), all 16B-aligned
  int*            esrc    = (int*)d_ws;                                  // NBKT*REGSZ   (9.8 MB)
  unsigned int*   bktdata = (unsigned int*)(esrc + (size_t)NBKT * REGSZ);// 196*196*96   (14.8 MB)
  int*            cnt     = (int*)(bktdata + (size_t)NBKT * NBLKA * CAPB); // NBKT*NBLKA (150 KB)
  unsigned short* h1b     = (unsigned short*)(cnt + NBKT * NBLKA);       // (N+1)*64 bf16 (12.8 MB)
  unsigned short* ab      = h1b + (size_t)(N_NODES + 1) * HID;           // N*64 bf16   (12.8 MB)
  float*          dis     = (float*)(ab + (size_t)N_NODES * HID);        // N
  int*            start   = (int*)(dis + N_NODES);                       // N
  int*            endi    = start + N_NODES;                             // N
  unsigned short* gb      = h1b;   // reuse: h1b dead after agg1; row N stays zero

  k_pre<<<NBLKA + NGEMM1, 1024, 0, stream>>>(row, col, x, W1, bktdata, cnt, h1b);
  k_build2<<<NBKT, 1024, 0, stream>>>(cnt, bktdata, dis, start, endi, esrc, h1b);
  k_agg1<<<(N_NODES * 8 + 255) / 256, 256, 0, stream>>>(esrc, start, endi, dis, h1b, b1, ab);
  k_gemm2<<<(N_NODES + 63) / 64, 256, 0, stream>>>(ab, W2, dis, gb);
  k_agg2ls<<<(N_NODES * 8 + 255) / 256, 256, 0, stream>>>(esrc, start, endi, dis, gb, b2, out);
}

// Round 4
// 289.279 us; speedup vs baseline: 1.1161x; 1.1161x over previous
//
#include <hip/hip_runtime.h>
#include <math.h>

#define N_NODES 100000
#define N_EDGES 1600000
#define F_INDIM 256
#define HID 64
#define NCLS 40
#define NBKT 196         // ceil(N_NODES/512) coarse buckets of 512 dst nodes
#define BKT_CAP 10240    // per-bucket capacity (mean 8192 for uniform graph)
#define EPB 8192         // edges per block in k_binA
#define ESRC_CAP 1904640 // E + NBKT*(1536+4), rounded to mult of 4

typedef __attribute__((ext_vector_type(8))) short short8;
typedef __attribute__((ext_vector_type(4))) float floatx4;

// ---- bf16 helpers (RNE) ----
__device__ __forceinline__ unsigned short f2bf(float f) {
  unsigned u = __float_as_uint(f);
  unsigned r = (u + 0x7FFFu + ((u >> 16) & 1u)) >> 16;
  return (unsigned short)r;
}
// accumulate 8 packed bf16 (one 16B quad of a row) into 8 fp32 accumulators
__device__ __forceinline__ void add8(float* a, uint4 u) {
  a[0] += __uint_as_float(u.x << 16);
  a[1] += __uint_as_float(u.x & 0xFFFF0000u);
  a[2] += __uint_as_float(u.y << 16);
  a[3] += __uint_as_float(u.y & 0xFFFF0000u);
  a[4] += __uint_as_float(u.z << 16);
  a[5] += __uint_as_float(u.z & 0xFFFF0000u);
  a[6] += __uint_as_float(u.w << 16);
  a[7] += __uint_as_float(u.w & 0xFFFF0000u);
}

// ---------------- tiny init: zero bucket cursors + dummy row of h1b ----------------

__global__ __launch_bounds__(256) void k_zero(int* __restrict__ gcur,
                                              unsigned int* __restrict__ h1bw) {
  int t = threadIdx.x;
  if (t < NBKT) gcur[t] = 0;
  if (t < 32) h1bw[(size_t)N_NODES * 32 + t] = 0;   // zero row N_NODES (128 B)
}

// ---------------- phase A: coarse-bucket edges, clustered writes ----------------
// 1024 threads/block (16 waves/CU at grid=196=1 block/CU) to hide LDS-atomic
// and load latency; int4-vectorized edge reads.

__global__ __launch_bounds__(1024) void k_binA(const int* __restrict__ row,
                                               const int* __restrict__ col,
                                               int* __restrict__ gcur,
                                               unsigned int* __restrict__ bktdata) {
  __shared__ int hist[NBKT];
  __shared__ int cur[NBKT];
  __shared__ int gbase[NBKT];
  const int t = threadIdx.x;
  const int e0 = blockIdx.x * EPB;
  const int n = min(EPB, N_EDGES - e0);
  if (t < NBKT) hist[t] = 0;
  __syncthreads();
  for (int i = t * 4; i < n; i += 4096) {
    int4 c4 = *(const int4*)&col[e0 + i];
    atomicAdd(&hist[c4.x >> 9], 1);
    atomicAdd(&hist[c4.y >> 9], 1);
    atomicAdd(&hist[c4.z >> 9], 1);
    atomicAdd(&hist[c4.w >> 9], 1);
  }
  __syncthreads();
  if (t < NBKT) {
    cur[t] = 0;
    int h = hist[t];
    gbase[t] = (h > 0) ? atomicAdd(&gcur[t], h) : 0;
  }
  __syncthreads();
  for (int i = t * 4; i < n; i += 4096) {
    int4 c4 = *(const int4*)&col[e0 + i];
    int4 r4 = *(const int4*)&row[e0 + i];
#pragma unroll
    for (int k = 0; k < 4; ++k) {
      int c = (k == 0) ? c4.x : (k == 1) ? c4.y : (k == 2) ? c4.z : c4.w;
      int r = (k == 0) ? r4.x : (k == 1) ? r4.y : (k == 2) ? r4.z : r4.w;
      int b = c >> 9;
      int p = atomicAdd(&cur[b], 1);
      bktdata[(size_t)b * BKT_CAP + gbase[b] + p] =
          ((unsigned)(c & 511) << 17) | (unsigned)r;
    }
  }
}

// ---------------- phase B (fused): hist + dis + padded scan + placement ----------
// 1024 threads/block; segments padded to multiples of 4 (pad = dummy node).

__global__ __launch_bounds__(1024) void k_build2(const int* __restrict__ gcur,
                                                 const unsigned int* __restrict__ bktdata,
                                                 float* __restrict__ dis,
                                                 int* __restrict__ start,
                                                 int* __restrict__ endi,
                                                 int* __restrict__ esrc) {
  __shared__ int h[512];
  __shared__ int cur[512];
  __shared__ int sbase[512];
  __shared__ int wsum[4];
  const int b = blockIdx.x, t = threadIdx.x;
  if (t < 512) { h[t] = 0; cur[t] = 0; }
  // padded base for this bucket (threads 0..255 compute it)
  if (t < 256) {
    int pv = (t < b) ? (((gcur[t] + 3) & ~3) + 1536) : 0;
#pragma unroll
    for (int off = 1; off < 64; off <<= 1) pv += __shfl_xor(pv, off);
    if ((t & 63) == 0) wsum[t >> 6] = pv;
  }
  __syncthreads();
  const int base = wsum[0] + wsum[1] + wsum[2] + wsum[3];

  const int cnt = gcur[b];
  const unsigned int* p = bktdata + (size_t)b * BKT_CAP;
  for (int i = t; i < cnt; i += 1024) atomicAdd(&h[p[i] >> 17], 1);
  __syncthreads();

  int c0 = 0, p0 = 0;
  if (t < 512) {
    const int n0 = b * 512 + t;
    c0 = h[t];
    p0 = (c0 + 3) & ~3;
    if (n0 < N_NODES) dis[n0] = rsqrtf((float)(c0 + 1));
    h[t] = p0;                           // scan PADDED counts
  }
  __syncthreads();
  // inclusive Hillis-Steele over 512 entries (first 512 threads)
#pragma unroll
  for (int off = 1; off < 512; off <<= 1) {
    int u = (t < 512 && t >= off) ? h[t - off] : 0;
    __syncthreads();
    if (t < 512) h[t] += u;
    __syncthreads();
  }
  if (t < 512) {
    const int n0 = b * 512 + t;
    const int sb0 = base + h[t] - p0;    // exclusive padded start (4-aligned)
    sbase[t] = sb0;
    if (n0 < N_NODES) { start[n0] = sb0; endi[n0] = sb0 + c0; }
    for (int k = c0; k < p0; ++k) esrc[sb0 + k] = N_NODES;   // dummy fill
    if (b == 0 && t == 0) start[N_NODES] = N_EDGES;          // sentinel (unused)
  }
  __syncthreads();

  for (int i = t; i < cnt; i += 1024) {
    unsigned u = p[i];
    int ld = u >> 17;
    int src = u & 0x1FFFF;
    int pos = sbase[ld] + atomicAdd(&cur[ld], 1);
    esrc[pos] = src;
  }
}

// ---------------- GEMM1 (MFMA): h1b = bf16(dis[row] * (x @ W1)) ----------------
// A-fragments direct from global (x has zero cross-block reuse); W1^T in LDS.

#define KP 264   // padded k-stride for wt (2-way bank aliasing only = free)

__global__ __launch_bounds__(256) void k_gemm1(const float* __restrict__ x,
                                               const float* __restrict__ W1,
                                               const float* __restrict__ dis,
                                               unsigned short* __restrict__ h1b) {
  __shared__ unsigned short wt[HID * KP];   // wt[n][k] = bf16(W1[k][n])
  const int tid = threadIdx.x;
  const int lane = tid & 63;
  const int w = tid >> 6;
  const int quad = lane >> 4;
  const int l15 = lane & 15;
  const int rowBase = blockIdx.x * 64;

#pragma unroll
  for (int i = 0; i < 16; ++i) {
    int f = tid + 256 * i;
    int k = f >> 4;
    int n0 = (f & 15) * 4;
    float4 v = *(const float4*)&W1[(size_t)k * HID + n0];
    wt[(n0 + 0) * KP + k] = f2bf(v.x);
    wt[(n0 + 1) * KP + k] = f2bf(v.y);
    wt[(n0 + 2) * KP + k] = f2bf(v.z);
    wt[(n0 + 3) * KP + k] = f2bf(v.w);
  }
  __syncthreads();

  const int ar = rowBase + w * 16 + l15;
  const float* xrow = x + (size_t)((ar < N_NODES) ? ar : N_NODES - 1) * F_INDIM + quad * 8;

  floatx4 acc[4];
#pragma unroll
  for (int c = 0; c < 4; ++c) acc[c] = (floatx4){0.f, 0.f, 0.f, 0.f};

#pragma unroll
  for (int kc = 0; kc < F_INDIM; kc += 32) {
    const float4 va = *(const float4*)(xrow + kc);
    const float4 vb = *(const float4*)(xrow + kc + 4);
    short8 a;
    a[0] = (short)f2bf(va.x); a[1] = (short)f2bf(va.y);
    a[2] = (short)f2bf(va.z); a[3] = (short)f2bf(va.w);
    a[4] = (short)f2bf(vb.x); a[5] = (short)f2bf(vb.y);
    a[6] = (short)f2bf(vb.z); a[7] = (short)f2bf(vb.w);
#pragma unroll
    for (int c = 0; c < 4; ++c) {
      const short8 b = *(const short8*)&wt[(c * 16 + l15) * KP + kc + quad * 8];
      acc[c] = __builtin_amdgcn_mfma_f32_16x16x32_bf16(a, b, acc[c], 0, 0, 0);
    }
  }

#pragma unroll
  for (int reg = 0; reg < 4; ++reg) {
    int gr = rowBase + w * 16 + quad * 4 + reg;
    if (gr < N_NODES) {
      float d = dis[gr];
#pragma unroll
      for (int c = 0; c < 4; ++c)
        h1b[(size_t)gr * HID + c * 16 + l15] = f2bf(d * acc[c][reg]);
    }
  }
}

// ---------------- agg1: ab = bf16(relu(dis[n]*(self+sum) + b1)) ----------------
// one node per 8-lane group; 8 edges in flight (2x int4 esrc + 8 row gathers).

__global__ __launch_bounds__(256) void k_agg1(const int* __restrict__ esrc,
                                              const int* __restrict__ start,
                                              const int* __restrict__ endi,
                                              const float* __restrict__ dis,
                                              const unsigned short* __restrict__ h1b,
                                              const float* __restrict__ b1,
                                              unsigned short* __restrict__ ab) {
  int gid = blockIdx.x * 256 + threadIdx.x;
  int node = gid >> 3;
  int q = gid & 7;
  if (node >= N_NODES) return;
  const uint4* hp4 = (const uint4*)h1b;    // row = 8 quads of 16B
  const int s = start[node];
  const int epad = (endi[node] + 3) & ~3;
  float acc[8];
#pragma unroll
  for (int j = 0; j < 8; ++j) acc[j] = 0.f;
  int i = s;
  for (; i + 8 <= epad; i += 8) {
    int4 sa = *(const int4*)&esrc[i];
    int4 sb = *(const int4*)&esrc[i + 4];
    uint4 u0 = hp4[(size_t)sa.x * 8 + q];
    uint4 u1 = hp4[(size_t)sa.y * 8 + q];
    uint4 u2 = hp4[(size_t)sa.z * 8 + q];
    uint4 u3 = hp4[(size_t)sa.w * 8 + q];
    uint4 u4 = hp4[(size_t)sb.x * 8 + q];
    uint4 u5 = hp4[(size_t)sb.y * 8 + q];
    uint4 u6 = hp4[(size_t)sb.z * 8 + q];
    uint4 u7 = hp4[(size_t)sb.w * 8 + q];
    add8(acc, u0); add8(acc, u1); add8(acc, u2); add8(acc, u3);
    add8(acc, u4); add8(acc, u5); add8(acc, u6); add8(acc, u7);
  }
  if (i < epad) {                          // exactly 4 remain
    int4 sv = *(const int4*)&esrc[i];
    uint4 u0 = hp4[(size_t)sv.x * 8 + q];
    uint4 u1 = hp4[(size_t)sv.y * 8 + q];
    uint4 u2 = hp4[(size_t)sv.z * 8 + q];
    uint4 u3 = hp4[(size_t)sv.w * 8 + q];
    add8(acc, u0); add8(acc, u1); add8(acc, u2); add8(acc, u3);
  }
  uint4 us = hp4[(size_t)node * 8 + q];
  add8(acc, us);                           // self term (pre-scaled)
  float d = dis[node];
  float4 ba = *(const float4*)&b1[q * 8];
  float4 bb = *(const float4*)&b1[q * 8 + 4];
  float v0 = fmaxf(d * acc[0] + ba.x, 0.f);
  float v1 = fmaxf(d * acc[1] + ba.y, 0.f);
  float v2 = fmaxf(d * acc[2] + ba.z, 0.f);
  float v3 = fmaxf(d * acc[3] + ba.w, 0.f);
  float v4 = fmaxf(d * acc[4] + bb.x, 0.f);
  float v5 = fmaxf(d * acc[5] + bb.y, 0.f);
  float v6 = fmaxf(d * acc[6] + bb.z, 0.f);
  float v7 = fmaxf(d * acc[7] + bb.w, 0.f);
  uint4 o;
  o.x = (unsigned)f2bf(v0) | ((unsigned)f2bf(v1) << 16);
  o.y = (unsigned)f2bf(v2) | ((unsigned)f2bf(v3) << 16);
  o.z = (unsigned)f2bf(v4) | ((unsigned)f2bf(v5) << 16);
  o.w = (unsigned)f2bf(v6) | ((unsigned)f2bf(v7) << 16);
  ((uint4*)ab)[(size_t)node * 8 + q] = o;
}

// ---------------- GEMM2 (MFMA): gb = bf16(dis[row] * (ab @ W2)), rows padded 64 ----
// cols 40..47 genuine zeros via padded W2; cols 48..63 never read (agg2 gathers q<5).

#define AP 72    // padded k-stride

__global__ __launch_bounds__(256) void k_gemm2(const unsigned short* __restrict__ ab,
                                               const float* __restrict__ W2,
                                               const float* __restrict__ dis,
                                               unsigned short* __restrict__ gb) {
  __shared__ unsigned short as[64 * AP];
  __shared__ unsigned short w2t[48 * AP];   // w2t[n][k] = bf16(W2[k][n]), 0-pad n>=40
  const int tid = threadIdx.x;
  const int lane = tid & 63;
  const int w = tid >> 6;
  const int quad = lane >> 4;
  const int l15 = lane & 15;
  const int rowBase = blockIdx.x * 64;

  for (int i = tid; i < 48 * 64; i += 256) {
    int n = i >> 6;
    int k = i & 63;
    w2t[n * AP + k] = (n < NCLS) ? f2bf(W2[(size_t)k * NCLS + n]) : (unsigned short)0;
  }
#pragma unroll
  for (int i = 0; i < 2; ++i) {
    int f = tid + 256 * i;
    int r = f >> 3;
    int q = f & 7;
    int gr = rowBase + r;
    short8 v = (short8){0, 0, 0, 0, 0, 0, 0, 0};
    if (gr < N_NODES) v = *(const short8*)&ab[(size_t)gr * HID + q * 8];
    *(short8*)&as[r * AP + q * 8] = v;
  }
  __syncthreads();

  floatx4 acc[3];
#pragma unroll
  for (int c = 0; c < 3; ++c) acc[c] = (floatx4){0.f, 0.f, 0.f, 0.f};

#pragma unroll
  for (int kh = 0; kh < 2; ++kh) {
    const short8 a = *(const short8*)&as[(w * 16 + l15) * AP + kh * 32 + quad * 8];
#pragma unroll
    for (int c = 0; c < 3; ++c) {
      const short8 b = *(const short8*)&w2t[(c * 16 + l15) * AP + kh * 32 + quad * 8];
      acc[c] = __builtin_amdgcn_mfma_f32_16x16x32_bf16(a, b, acc[c], 0, 0, 0);
    }
  }

#pragma unroll
  for (int reg = 0; reg < 4; ++reg) {
    int gr = rowBase + w * 16 + quad * 4 + reg;
    if (gr < N_NODES) {
      float d = dis[gr];
#pragma unroll
      for (int c = 0; c < 3; ++c) {
        int cc = c * 16 + l15;   // cols 0..47 (40..47 genuinely zero via padded W2)
        gb[(size_t)gr * 64 + cc] = f2bf(d * acc[c][reg]);
      }
      // cols 48..63 intentionally NOT written: agg2 only gathers quads q<5
    }
  }
}

// ---------------- agg2 + log_softmax fused: one node per 8-lane group ----------
// ONLY lanes q<5 gather (bytes 0..79 = the 40 real classes): 37.5% less gather traffic.

__global__ __launch_bounds__(256) void k_agg2ls(const int* __restrict__ esrc,
                                                const int* __restrict__ start,
                                                const int* __restrict__ endi,
                                                const float* __restrict__ dis,
                                                const unsigned short* __restrict__ gb,
                                                const float* __restrict__ b2,
                                                float* __restrict__ out) {
  int gid = blockIdx.x * 256 + threadIdx.x;
  int node = gid >> 3;
  int q = gid & 7;
  if (node >= N_NODES) return;
  const bool wr = q < 5;
  float acc[8];
#pragma unroll
  for (int j = 0; j < 8; ++j) acc[j] = 0.f;
  if (wr) {
    const uint4* gp4 = (const uint4*)gb;
    const int s = start[node];
    const int epad = (endi[node] + 3) & ~3;
    int i = s;
    for (; i + 8 <= epad; i += 8) {
      int4 sa = *(const int4*)&esrc[i];
      int4 sb = *(const int4*)&esrc[i + 4];
      uint4 u0 = gp4[(size_t)sa.x * 8 + q];
      uint4 u1 = gp4[(size_t)sa.y * 8 + q];
      uint4 u2 = gp4[(size_t)sa.z * 8 + q];
      uint4 u3 = gp4[(size_t)sa.w * 8 + q];
      uint4 u4 = gp4[(size_t)sb.x * 8 + q];
      uint4 u5 = gp4[(size_t)sb.y * 8 + q];
      uint4 u6 = gp4[(size_t)sb.z * 8 + q];
      uint4 u7 = gp4[(size_t)sb.w * 8 + q];
      add8(acc, u0); add8(acc, u1); add8(acc, u2); add8(acc, u3);
      add8(acc, u4); add8(acc, u5); add8(acc, u6); add8(acc, u7);
    }
    if (i < epad) {                          // exactly 4 remain
      int4 sv = *(const int4*)&esrc[i];
      uint4 u0 = gp4[(size_t)sv.x * 8 + q];
      uint4 u1 = gp4[(size_t)sv.y * 8 + q];
      uint4 u2 = gp4[(size_t)sv.z * 8 + q];
      uint4 u3 = gp4[(size_t)sv.w * 8 + q];
      add8(acc, u0); add8(acc, u1); add8(acc, u2); add8(acc, u3);
    }
    uint4 us = gp4[(size_t)node * 8 + q];
    add8(acc, us);                           // self (pre-scaled in gb)
  }
  float v0 = 0.f, v1 = 0.f, v2 = 0.f, v3 = 0.f, v4 = 0.f, v5 = 0.f, v6 = 0.f, v7 = 0.f;
  float m = -INFINITY;
  if (wr) {
    float d = dis[node];
    float4 ba = *(const float4*)&b2[q * 8];
    float4 bb = *(const float4*)&b2[q * 8 + 4];
    v0 = d * acc[0] + ba.x;
    v1 = d * acc[1] + ba.y;
    v2 = d * acc[2] + ba.z;
    v3 = d * acc[3] + ba.w;
    v4 = d * acc[4] + bb.x;
    v5 = d * acc[5] + bb.y;
    v6 = d * acc[6] + bb.z;
    v7 = d * acc[7] + bb.w;
    m = fmaxf(fmaxf(fmaxf(v0, v1), fmaxf(v2, v3)),
              fmaxf(fmaxf(v4, v5), fmaxf(v6, v7)));
  }
  // reduce max/sum within the 8-lane group (offsets 1,2,4 stay inside group)
#pragma unroll
  for (int off = 1; off < 8; off <<= 1) m = fmaxf(m, __shfl_xor(m, off));
  float el = 0.f;
  if (wr) {
    el = __expf(v0 - m) + __expf(v1 - m) + __expf(v2 - m) + __expf(v3 - m) +
         __expf(v4 - m) + __expf(v5 - m) + __expf(v6 - m) + __expf(v7 - m);
  }
#pragma unroll
  for (int off = 1; off < 8; off <<= 1) el += __shfl_xor(el, off);
  float ls = logf(el);
  if (wr) {
    float4 o1 = make_float4(v0 - m - ls, v1 - m - ls, v2 - m - ls, v3 - m - ls);
    float4 o2 = make_float4(v4 - m - ls, v5 - m - ls, v6 - m - ls, v7 - m - ls);
    *(float4*)&out[(size_t)node * NCLS + q * 8] = o1;
    *(float4*)&out[(size_t)node * NCLS + q * 8 + 4] = o2;
  }
}

// ---------------- launch ----------------

extern "C" void kernel_launch(void* const* d_in, const int* in_sizes, int n_in,
                              void* d_out, int out_size, void* d_ws, size_t ws_size,
                              hipStream_t stream) {
  const float* x  = (const float*)d_in[0];
  const int*   ei = (const int*)d_in[1];
  const float* W1 = (const float*)d_in[2];
  const float* b1 = (const float*)d_in[3];
  const float* W2 = (const float*)d_in[4];
  const float* b2 = (const float*)d_in[5];
  float* out = (float*)d_out;

  const int* row = ei;             // edge_index[0] = src
  const int* col = ei + N_EDGES;   // edge_index[1] = dst

  // workspace layout (~43 MB)
  int*            esrc    = (int*)d_ws;                            // ESRC_CAP ints (7.6 MB)
  unsigned int*   bktdata = (unsigned int*)(esrc + ESRC_CAP);      // NBKT*CAP      (8.0 MB)
  unsigned short* h1b     = (unsigned short*)(bktdata + (size_t)NBKT * BKT_CAP); // (N+1)*64 bf16
  unsigned short* ab      = h1b + (size_t)(N_NODES + 1) * HID;     // N*64 bf16   (12.8 MB)
  float*          dis     = (float*)(ab + (size_t)N_NODES * HID);  // N
  int*            start   = (int*)(dis + N_NODES);                 // N+1
  int*            endi    = start + N_NODES + 1;                   // N
  int*            gcur    = endi + N_NODES;                        // NBKT
  unsigned short* gb      = h1b;                                   // (N+1)*64 bf16, reuse

  k_zero<<<1, 256, 0, stream>>>(gcur, (unsigned int*)h1b);
  k_binA<<<(N_EDGES + EPB - 1) / EPB, 1024, 0, stream>>>(row, col, gcur, bktdata);
  k_build2<<<NBKT, 1024, 0, stream>>>(gcur, bktdata, dis, start, endi, esrc);

  k_gemm1<<<(N_NODES + 63) / 64, 256, 0, stream>>>(x, W1, dis, h1b);
  k_agg1<<<(N_NODES * 8 + 255) / 256, 256, 0, stream>>>(esrc, start, endi, dis, h1b, b1, ab);

  k_gemm2<<<(N_NODES + 63) / 64, 256, 0, stream>>>(ab, W2, dis, gb);
  k_agg2ls<<<(N_NODES * 8 + 255) / 256, 256, 0, stream>>>(esrc, start, endi, dis, gb, b2, out);
}